// Round 3
// baseline (45.404 us; speedup 1.0000x reference)
//
#include <hip/hip_runtime.h>
#include <math.h>

typedef _Float16 half8 __attribute__((ext_vector_type(8)));
typedef float f32x4 __attribute__((ext_vector_type(4)));

#define DIMK 2048
#define NEXP 64
#define BM 16                 // rows per block (one 16x16x32 A-tile)
#define KSPLIT 4              // waves per block, k-split
#define KPW (DIMK / KSPLIT)   // 512 k per wave
#define NKS (KPW / 32)        // 16 ksteps of K=32

// ---------------- W pre-split kernel ----------------
// ws layout (halfs): frag block = [kb32][limb][et] of 512 halfs; within: [lane][kj]
// lane = ((k>>3)&3)*16 + (e&15); element k = kb32*32 + (lane>>4)*8 + kj
__global__ void SwitchRouter_wsplit(const float* __restrict__ W, _Float16* __restrict__ ws) {
    int t = blockIdx.x * 256 + threadIdx.x;
    if (t >= NEXP * DIMK) return;
    int e = t >> 11, k = t & (DIMK - 1);
    float w = W[e * DIMK + k];
    _Float16 h0 = (_Float16)w;
    _Float16 h1 = (_Float16)(w - (float)h0);
    int kb32 = k >> 5;
    int lane = (((k >> 3) & 3) << 4) | (e & 15);
    int et   = e >> 4;
    size_t base = ((size_t)(kb32 * 2 + 0) * 4 + et) * 512 + lane * 8 + (k & 7);
    ws[base]        = h0;   // limb 0 (hi)
    ws[base + 2048] = h1;   // limb 1 (lo): +4*512 halfs
}

__device__ __forceinline__ bool gt_pair(float v, int i, float v2, int i2) {
    return (v > v2) || (v == v2 && i < i2);
}

__global__ __launch_bounds__(256, 4)
void SwitchRouter_43078521979510_kernel(const float* __restrict__ x,
                                        const _Float16* __restrict__ ws,
                                        const float* __restrict__ bias,
                                        float* __restrict__ out, int M)
{
    __shared__ float red[KSPLIT * BM * 68];  // 4*16*68 floats = 17408 B

    const int t    = threadIdx.x;
    const int wv   = t >> 6;
    const int lane = t & 63;
    const int r0   = blockIdx.x * BM;

    // A: lane reads its own row's contiguous 8-float k-slices (fragment layout direct)
    const float* xr = x + (size_t)(r0 + (lane & 15)) * DIMK + wv * KPW + ((lane >> 4) << 3);
    // W: per (kstep, q=limb*4+et) frag at wp + ks*4096 + q*512 (halfs), lane-contiguous
    const _Float16* wp = ws + (size_t)(wv * NKS) * 4096 + lane * 8;

    f32x4 acc[4] = {};

    // A ring buffer, 4 ksteps deep (HBM latency cover); W single-buffered (L2 + TLP)
    float4 fa[4], fb[4];
#pragma unroll
    for (int d = 0; d < 4; ++d) {
        fa[d] = *(const float4*)(xr + d * 32);
        fb[d] = *(const float4*)(xr + d * 32 + 4);
    }

#pragma unroll
    for (int ks = 0; ks < NKS; ++ks) {
        half8 w[8];
#pragma unroll
        for (int q = 0; q < 8; ++q)
            w[q] = *(const half8*)(wp + (size_t)ks * 4096 + q * 512);

        const float4 va = fa[ks & 3], vb = fb[ks & 3];
        const float f[8] = {va.x, va.y, va.z, va.w, vb.x, vb.y, vb.z, vb.w};
        half8 a0, a1;
#pragma unroll
        for (int i = 0; i < 8; ++i) {
            _Float16 h = (_Float16)f[i];
            a0[i] = h;
            a1[i] = (_Float16)(f[i] - (float)h);
        }

#pragma unroll
        for (int et = 0; et < 4; ++et) {
            acc[et] = __builtin_amdgcn_mfma_f32_16x16x32_f16(a0, w[et],     acc[et], 0, 0, 0); // a0*Whi
            acc[et] = __builtin_amdgcn_mfma_f32_16x16x32_f16(a1, w[et],     acc[et], 0, 0, 0); // a1*Whi
            acc[et] = __builtin_amdgcn_mfma_f32_16x16x32_f16(a0, w[4 + et], acc[et], 0, 0, 0); // a0*Wlo
        }

        if (ks + 4 < NKS) {
            fa[ks & 3] = *(const float4*)(xr + (ks + 4) * 32);
            fb[ks & 3] = *(const float4*)(xr + (ks + 4) * 32 + 4);
        }
    }

    // ---------------- cross-wave K reduction via LDS ----------------
    // D layout (16x16x32): col = lane&15 (expert within et group), row m = (lane>>4)*4 + r
#pragma unroll
    for (int et = 0; et < 4; ++et)
#pragma unroll
        for (int r = 0; r < 4; ++r) {
            const int m = ((lane >> 4) << 2) + r;
            const int e = (et << 4) + (lane & 15);
            red[(wv * BM + m) * 68 + e] = acc[et][r];
        }
    __syncthreads();

    // ---------------- epilogue: bias + top-2 + softmax (validated path) ----------------
    if (t < BM * 8) {
        const int row = t >> 3;   // 0..15
        const int g8  = t & 7;    // expert group of 8
        float l[8];
#pragma unroll
        for (int j = 0; j < 8; ++j) {
            float s = 0.f;
#pragma unroll
            for (int w2 = 0; w2 < KSPLIT; ++w2) s += red[(w2 * BM + row) * 68 + g8 * 8 + j];
            l[j] = s + bias[g8 * 8 + j];
        }

        float v0 = l[0];
        int   i0 = 8 * g8;
        float v1 = -INFINITY;
        int   i1 = -1;
#pragma unroll
        for (int j = 1; j < 8; ++j) {
            const float lv = l[j];
            const int   e  = 8 * g8 + j;
            if (lv > v0) { v1 = v0; i1 = i0; v0 = lv; i0 = e; }
            else if (lv > v1) { v1 = lv; i1 = e; }
        }
#pragma unroll
        for (int m = 1; m <= 4; m <<= 1) {
            const float ov0 = __shfl_xor(v0, m);
            const int   oi0 = __shfl_xor(i0, m);
            const float ov1 = __shfl_xor(v1, m);
            const int   oi1 = __shfl_xor(i1, m);
            if (gt_pair(ov0, oi0, v0, i0)) {
                if (gt_pair(v0, i0, ov1, oi1)) { v1 = v0; i1 = i0; }
                else                           { v1 = ov1; i1 = oi1; }
                v0 = ov0; i0 = oi0;
            } else if (gt_pair(ov0, oi0, v1, i1)) {
                v1 = ov0; i1 = oi0;
            }
        }
        float d = 0.f;
#pragma unroll
        for (int j = 0; j < 8; ++j) d += expf(l[j] - v0);
#pragma unroll
        for (int m = 1; m <= 4; m <<= 1) d += __shfl_xor(d, m);

        if (g8 == 0) {
            const int R = r0 + row;
            out[2 * R]     = (float)i0;
            out[2 * R + 1] = (float)i1;
            out[2 * M + 2 * R]     = 1.f / d;
            out[2 * M + 2 * R + 1] = expf(v1 - v0) / d;
        }
    }
}

extern "C" void kernel_launch(void* const* d_in, const int* in_sizes, int n_in,
                              void* d_out, int out_size, void* d_ws, size_t ws_size,
                              hipStream_t stream) {
    const float* x  = (const float*)d_in[0];
    const float* W  = (const float*)d_in[1];
    const float* b  = (const float*)d_in[2];
    float* out = (float*)d_out;
    _Float16* ws = (_Float16*)d_ws;
    const int M = in_sizes[0] / DIMK;   // 16384 rows

    SwitchRouter_wsplit<<<(NEXP * DIMK + 255) / 256, 256, 0, stream>>>(W, ws);
    SwitchRouter_43078521979510_kernel<<<M / BM, 256, 0, stream>>>(x, ws, b, out, M);
}